// Round 18
// baseline (389.485 us; speedup 1.0000x reference)
//
#include <hip/hip_runtime.h>
#include <hip/hip_bf16.h>

#define B_ 128
#define L_ 1024
#define T_ 64
#define CSH 5
#define C_ 32

using short8 = __attribute__((ext_vector_type(8))) short;
using f32x4  = __attribute__((ext_vector_type(4))) float;
using f32x16 = __attribute__((ext_vector_type(16))) float;

static __device__ __forceinline__ unsigned short bfb(float x) {
  return __builtin_bit_cast(unsigned short, __float2bfloat16(x));
}
static __device__ __forceinline__ float asf(unsigned u) { return __builtin_bit_cast(float, u); }
static __device__ __forceinline__ float bf2f(unsigned short b) { return asf(((unsigned)b) << 16); }
static __device__ __forceinline__ unsigned pk2(float lo, float hi) {
  __hip_bfloat162 h = __float22bfloat162_rn(float2{lo, hi});
  unsigned u;
  __builtin_memcpy(&u, &h, 4);
  return u;
}
// packed 2xf32 -> bf16x2 dword by TRUNCATION: one v_perm_b32 (verified r8)
static __device__ __forceinline__ unsigned pk2t(float lo, float hi) {
  return __builtin_amdgcn_perm(__builtin_bit_cast(unsigned, hi),
                               __builtin_bit_cast(unsigned, lo), 0x07060302u);
}
// gfx950 half-wave exchange (verified r5)
static __device__ __forceinline__ void pswap(unsigned& x, unsigned& y) {
  asm("v_permlane32_swap_b32 %0, %1" : "+v"(x), "+v"(y));
}

// ---------- K0: build Wswz table + zero score/cnt/out ----------
__global__ __launch_bounds__(256) void k_prep(const float* __restrict__ W,
                                              unsigned short* __restrict__ Wswz,
                                              float* __restrict__ score,
                                              unsigned* __restrict__ cnt,
                                              float* __restrict__ out) {
  if (blockIdx.x == 0) {
    if (threadIdx.x < 128) score[threadIdx.x] = 0.f;
    else cnt[threadIdx.x - 128] = 0u;
    if (threadIdx.x == 0) out[0] = 0.f;
  }
  const int t = blockIdx.x * 256 + threadIdx.x;
  const int e = t * 4, k = e >> 6, n0 = e & 63;
  float4 w4 = *(const float4*)(W + e);
  const int base = ((k >> 5) << 11) + ((n0 >> 4) << 9) + (((k >> 3) & 3) << 7) +
                   ((n0 & 15) << 3) + (k & 7);
  Wswz[base + 0]  = bfb(w4.x);
  Wswz[base + 8]  = bfb(w4.y);
  Wswz[base + 16] = bfb(w4.z);
  Wswz[base + 24] = bfb(w4.w);
}

// ---------- K1: emission + scan + distributed gold + last-block TREE tail ----------
__global__ __launch_bounds__(256) void k_scan(const int* __restrict__ x,
                                              const int* __restrict__ tags,
                                              const float* __restrict__ embed,
                                              const unsigned short* __restrict__ Wswz,
                                              const float* __restrict__ W,
                                              const float* __restrict__ bias,
                                              const float* __restrict__ trans,
                                              unsigned short* __restrict__ XT,
                                              float* __restrict__ rlog,
                                              float* __restrict__ score,
                                              unsigned* __restrict__ cnt,
                                              float* __restrict__ out) {
  __shared__ __align__(16) unsigned short Ftile[4][2048];  // scan F-tiles (32x64 each)
  __shared__ __align__(16) unsigned short Ptile[4][4096];  // tail 64x64 P matrices
  // ^ r16/r17 NaN root cause: P (64x64 = 4096 ushorts) was stored into the
  //   2048-ushort Ftile, overrunning neighboring tiles / vS (LDS corruption).
  __shared__ __align__(16) float vS[64];
  __shared__ float tlg[4];
  __shared__ int isTail;
  const int wv = threadIdx.x >> 6, L = threadIdx.x & 63;
  const int job = blockIdx.x * 4 + wv;
  const int c = job & (C_ - 1);
  const int b = job >> CSH;
  const int K = (1023 + C_ - 1) >> CSH;
  const int a = 1 + c * K;
  const int len = min(K, 1024 - a);
  const int nh = L & 31, hh = L >> 5;
  const int m = L & 15, q = L >> 4;
  unsigned short* Ft = Ftile[wv];
  const int* tg = tags + (size_t)b * L_;

  // ---- emission prologue (r13-verified) ----
  const float bj0 = bias[m], bj1 = bias[16 + m], bj2 = bias[32 + m], bj3 = bias[48 + m];
  for (int p = 0; p < 2; p++) {
    int tok = a + 16 * p + m;
    if (tok > 1023) tok = 1023;
    const float* er = embed + (size_t)x[b * 1024 + tok] * 256;
    f32x4 acc[4] = {{0.f,0.f,0.f,0.f},{0.f,0.f,0.f,0.f},{0.f,0.f,0.f,0.f},{0.f,0.f,0.f,0.f}};
#pragma unroll
    for (int kap = 0; kap < 8; kap++) {
      float4 p0 = *(const float4*)(er + 32 * kap + 8 * q);
      float4 p1 = *(const float4*)(er + 32 * kap + 8 * q + 4);
      unsigned u0 = pk2(p0.x, p0.y), u1 = pk2(p0.z, p0.w);
      unsigned u2 = pk2(p1.x, p1.y), u3 = pk2(p1.z, p1.w);
      short8 af = __builtin_bit_cast(short8, make_uint4(u0, u1, u2, u3));
#pragma unroll
      for (int u = 0; u < 4; u++) {
        short8 bf8 = *(const short8*)&Wswz[kap * 2048 + u * 512 + q * 128 + m * 8];
        acc[u] = __builtin_amdgcn_mfma_f32_16x16x32_bf16(af, bf8, acc[u], 0, 0, 0);
      }
    }
#pragma unroll
    for (int r = 0; r < 4; r++) {
      float e0 = acc[0][r] + bj0, e1 = acc[1][r] + bj1;
      float e2 = acc[2][r] + bj2, e3 = acc[3][r] + bj3;
      float mr = fmaxf(fmaxf(e0, e1), fmaxf(e2, e3));
#pragma unroll
      for (int off = 1; off < 16; off <<= 1) mr = fmaxf(mr, __shfl_xor(mr, off));
      float x0 = __expf(e0 - mr), x1 = __expf(e1 - mr);
      float x2 = __expf(e2 - mr), x3 = __expf(e3 - mr);
      float sr = (x0 + x1) + (x2 + x3);
#pragma unroll
      for (int off = 1; off < 16; off <<= 1) sr += __shfl_xor(sr, off);
      float rs = 1.0f / sr;
      const int row = 16 * p + 4 * q + r;
      Ft[row * 64 + m]      = bfb(x0 * rs);
      Ft[row * 64 + 16 + m] = bfb(x1 * rs);
      Ft[row * 64 + 32 + m] = bfb(x2 * rs);
      Ft[row * 64 + 48 + m] = bfb(x3 * rs);
    }
  }
  // ---- distributed gold partials (r14-verified) ----
  {
    float gold = 0.f;
    if (L < len) {
      const int tga = tg[a + L], tgp = tg[a - 1 + L];
      gold = __logf(bf2f(Ft[L * 64 + tga])) + trans[tgp * T_ + tga];
    }
#pragma unroll
    for (int off = 1; off < 64; off <<= 1) gold += __shfl_xor(gold, off);
    if (L == 0) atomicAdd(&score[b], gold);
  }

  // ---- A = E^T frags / B = identity (r13-verified) ----
  short8 Af[2][4];
#pragma unroll
  for (int I = 0; I < 2; I++)
#pragma unroll
    for (int kap = 0; kap < 4; kap++) {
      short8 aa;
#pragma unroll
      for (int d = 0; d < 8; d++) {
        const int k = 16 * kap + 8 * hh + d;
        aa[d] = (short)bfb(__expf(trans[k * T_ + 32 * I + nh]));
      }
      Af[I][kap] = aa;
    }
  unsigned Bf[4][2][4];
#pragma unroll
  for (int kap = 0; kap < 4; kap++)
#pragma unroll
    for (int J = 0; J < 2; J++)
#pragma unroll
      for (int dw = 0; dw < 4; dw++) {
        int k0 = 16 * kap + 8 * hh + 2 * dw, n = 32 * J + nh;
        unsigned u = 0;
        if (k0 == n) u = 0x3F80u;
        if (k0 + 1 == n) u = 0x3F800000u;
        Bf[kap][J][dw] = u;
      }

  float logacc = 0.f;
  const f32x16 Z = {};
  for (int s = 0; s < len; s++) {  // --- r13-verified scan loop ---
    uint2 Fc[2][4];
#pragma unroll
    for (int I = 0; I < 2; I++)
#pragma unroll
      for (int j = 0; j < 4; j++)
        Fc[I][j] = *(const uint2*)&Ft[s * 64 + (16 * I + 4 * j + 2 * hh) * 2];
    const bool rn = ((s & 15) == 15);
    float rs = 1.0f;
#pragma unroll
    for (int J = 0; J < 2; J++) {
      f32x16 D[2];
#pragma unroll
      for (int I = 0; I < 2; I++) {
        short8 b0 = __builtin_bit_cast(short8,
            make_uint4(Bf[0][J][0], Bf[0][J][1], Bf[0][J][2], Bf[0][J][3]));
        f32x16 d = __builtin_amdgcn_mfma_f32_32x32x16_bf16(Af[I][0], b0, Z, 0, 0, 0);
#pragma unroll
        for (int kap = 1; kap < 4; kap++) {
          short8 bk = __builtin_bit_cast(short8,
              make_uint4(Bf[kap][J][0], Bf[kap][J][1], Bf[kap][J][2], Bf[kap][J][3]));
          d = __builtin_amdgcn_mfma_f32_32x32x16_bf16(Af[I][kap], bk, d, 0, 0, 0);
        }
        D[I] = d;
      }
#pragma unroll
      for (int I = 0; I < 2; I++)
#pragma unroll
        for (int j = 0; j < 4; j++) {
          uint2 g = Fc[I][j];
          float f0 = asf(g.x << 16), f1 = asf(g.x & 0xffff0000u);
          float f2 = asf(g.y << 16), f3 = asf(g.y & 0xffff0000u);
          D[I][4 * j + 0] *= f0;
          D[I][4 * j + 1] *= f1;
          D[I][4 * j + 2] *= f2;
          D[I][4 * j + 3] *= f3;
        }
      if (rn) {
        if (J == 0) {
          float mx = D[0][0];
#pragma unroll
          for (int I = 0; I < 2; I++)
#pragma unroll
            for (int r = 0; r < 16; r++) mx = fmaxf(mx, D[I][r]);
#pragma unroll
          for (int off = 1; off < 64; off <<= 1) mx = fmaxf(mx, __shfl_xor(mx, off));
          rs = 1.0f / mx;
          logacc += __logf(mx);
        }
#pragma unroll
        for (int I = 0; I < 2; I++)
#pragma unroll
          for (int r = 0; r < 16; r++) D[I][r] *= rs;
      }
      unsigned PDt[2][4][2];
#pragma unroll
      for (int I = 0; I < 2; I++)
#pragma unroll
        for (int j = 0; j < 4; j++) {
          PDt[I][j][0] = pk2t(D[I][4 * j + 0], D[I][4 * j + 1]);
          PDt[I][j][1] = pk2t(D[I][4 * j + 2], D[I][4 * j + 3]);
        }
      if (s == len - 1) {
        unsigned short* Xrow = XT + (size_t)job * 4096 + 32 * J + nh;
#pragma unroll
        for (int I = 0; I < 2; I++)
#pragma unroll
          for (int j = 0; j < 4; j++)
#pragma unroll
            for (int pp = 0; pp < 2; pp++) {
              const int r = 32 * I + 8 * j + 4 * hh + 2 * pp;
              Xrow[(size_t)r * 64] = (unsigned short)(PDt[I][j][pp] & 0xffffu);
              Xrow[(size_t)(r + 1) * 64] = (unsigned short)(PDt[I][j][pp] >> 16);
            }
      } else {
#pragma unroll
        for (int kap = 0; kap < 4; kap++) {
          const int Ip = kap >> 1, e2 = 2 * (kap & 1);
          unsigned x0 = PDt[Ip][e2][0], y0 = PDt[Ip][e2 + 1][0];
          unsigned x1 = PDt[Ip][e2][1], y1 = PDt[Ip][e2 + 1][1];
          pswap(x0, y0);
          pswap(x1, y1);
          Bf[kap][J][0] = x0;
          Bf[kap][J][1] = x1;
          Bf[kap][J][2] = y0;
          Bf[kap][J][3] = y1;
        }
      }
    }
  }
  if (L == 0) rlog[job] = logacc;

  // ---- last-block-done protocol (r14-verified) ----
  __syncthreads();
  if (threadIdx.x == 0) {
    __threadfence();
    unsigned old = atomicAdd(&cnt[b], 1u);
    isTail = (old == 7u);
  }
  __syncthreads();
  if (!isTail) return;
  __threadfence();  // acquire

  // ==== TREE TAIL: T1 wave wv computes P_wv = X_{8wv+7}···X_{8wv} into Ptile[wv],
  // per-round renorm (log in plog). ====
  const unsigned short* Sb = XT + (size_t)b * C_ * 4096;
  {
    float plog = 0.f;
#pragma unroll
    for (int kap = 0; kap < 4; kap++)
#pragma unroll
      for (int J = 0; J < 2; J++)
#pragma unroll
        for (int dw = 0; dw < 4; dw++) {
          int k0 = 16 * kap + 8 * hh + 2 * dw, n = 32 * J + nh;
          unsigned u = 0;
          if (k0 == n) u = 0x3F80u;
          if (k0 + 1 == n) u = 0x3F800000u;
          Bf[kap][J][dw] = u;
        }
    for (int r = 0; r < 8; r++) {
      short8 Ap[2][4];
#pragma unroll
      for (int I = 0; I < 2; I++)
#pragma unroll
        for (int kap = 0; kap < 4; kap++)
          Ap[I][kap] = *(const short8*)(Sb + (size_t)(8 * wv + r) * 4096 +
                                        (32 * I + nh) * 64 + 16 * kap + 8 * hh);
      const bool last = (r == 7);
      float rsw = 1.0f;
#pragma unroll
      for (int J = 0; J < 2; J++) {
        f32x16 D[2];
#pragma unroll
        for (int I = 0; I < 2; I++) {
          short8 b0 = __builtin_bit_cast(short8,
              make_uint4(Bf[0][J][0], Bf[0][J][1], Bf[0][J][2], Bf[0][J][3]));
          f32x16 d = __builtin_amdgcn_mfma_f32_32x32x16_bf16(Ap[I][0], b0, Z, 0, 0, 0);
#pragma unroll
          for (int kap = 1; kap < 4; kap++) {
            short8 bk = __builtin_bit_cast(short8,
                make_uint4(Bf[kap][J][0], Bf[kap][J][1], Bf[kap][J][2], Bf[kap][J][3]));
            d = __builtin_amdgcn_mfma_f32_32x32x16_bf16(Ap[I][kap], bk, d, 0, 0, 0);
          }
          D[I] = d;
        }
        if (J == 0) {
          float mx = D[0][0];
#pragma unroll
          for (int I = 0; I < 2; I++)
#pragma unroll
            for (int rr = 0; rr < 16; rr++) mx = fmaxf(mx, D[I][rr]);
#pragma unroll
          for (int off = 1; off < 64; off <<= 1) mx = fmaxf(mx, __shfl_xor(mx, off));
          mx = fmaxf(mx, 1e-30f);
          rsw = 1.0f / mx;
          plog += __logf(mx);
        }
#pragma unroll
        for (int I = 0; I < 2; I++)
#pragma unroll
          for (int rr = 0; rr < 16; rr++) D[I][rr] *= rsw;
        unsigned PDt[2][4][2];
#pragma unroll
        for (int I = 0; I < 2; I++)
#pragma unroll
          for (int j = 0; j < 4; j++) {
            PDt[I][j][0] = pk2t(D[I][4 * j + 0], D[I][4 * j + 1]);
            PDt[I][j][1] = pk2t(D[I][4 * j + 2], D[I][4 * j + 3]);
          }
        if (last) {
          unsigned short* Xrow = Ptile[wv] + 32 * J + nh;  // 64x64 tile (4096 ushorts)
#pragma unroll
          for (int I = 0; I < 2; I++)
#pragma unroll
            for (int j = 0; j < 4; j++)
#pragma unroll
              for (int pp = 0; pp < 2; pp++) {
                const int rr = 32 * I + 8 * j + 4 * hh + 2 * pp;
                Xrow[rr * 64] = (unsigned short)(PDt[I][j][pp] & 0xffffu);
                Xrow[(rr + 1) * 64] = (unsigned short)(PDt[I][j][pp] >> 16);
              }
        } else {
#pragma unroll
          for (int kap = 0; kap < 4; kap++) {
            const int Ip = kap >> 1, e2 = 2 * (kap & 1);
            unsigned x0 = PDt[Ip][e2][0], y0 = PDt[Ip][e2 + 1][0];
            unsigned x1 = PDt[Ip][e2][1], y1 = PDt[Ip][e2 + 1][1];
            pswap(x0, y0);
            pswap(x1, y1);
            Bf[kap][J][0] = x0;
            Bf[kap][J][1] = x1;
            Bf[kap][J][2] = y0;
            Bf[kap][J][3] = y1;
          }
        }
      }
    }
    if (L == 0) tlg[wv] = plog;
  }
  __syncthreads();
  if (threadIdx.x >= 64) return;  // wave 0 finishes alone

  // T2: Zb = P_3 · P_2 · P_1 · P_0 from Ptile; per-round renorm + log.
  float tlog = (tlg[0] + tlg[1]) + (tlg[2] + tlg[3]);
  {
#pragma unroll
    for (int kap = 0; kap < 4; kap++)
#pragma unroll
      for (int J = 0; J < 2; J++)
#pragma unroll
        for (int dw = 0; dw < 4; dw++) {
          int k0 = 16 * kap + 8 * hh + 2 * dw, n = 32 * J + nh;
          unsigned u = 0;
          if (k0 == n) u = 0x3F80u;
          if (k0 + 1 == n) u = 0x3F800000u;
          Bf[kap][J][dw] = u;
        }
    for (int r = 0; r < 4; r++) {
      short8 Ap[2][4];
#pragma unroll
      for (int I = 0; I < 2; I++)
#pragma unroll
        for (int kap = 0; kap < 4; kap++)
          Ap[I][kap] = *(const short8*)&Ptile[r][(32 * I + nh) * 64 + 16 * kap + 8 * hh];
      const bool last = (r == 3);
      float rsw = 1.0f;
#pragma unroll
      for (int J = 0; J < 2; J++) {
        f32x16 D[2];
#pragma unroll
        for (int I = 0; I < 2; I++) {
          short8 b0 = __builtin_bit_cast(short8,
              make_uint4(Bf[0][J][0], Bf[0][J][1], Bf[0][J][2], Bf[0][J][3]));
          f32x16 d = __builtin_amdgcn_mfma_f32_32x32x16_bf16(Ap[I][0], b0, Z, 0, 0, 0);
#pragma unroll
          for (int kap = 1; kap < 4; kap++) {
            short8 bk = __builtin_bit_cast(short8,
                make_uint4(Bf[kap][J][0], Bf[kap][J][1], Bf[kap][J][2], Bf[kap][J][3]));
            d = __builtin_amdgcn_mfma_f32_32x32x16_bf16(Ap[I][kap], bk, d, 0, 0, 0);
          }
          D[I] = d;
        }
        if (J == 0) {
          float mx = D[0][0];
#pragma unroll
          for (int I = 0; I < 2; I++)
#pragma unroll
            for (int rr = 0; rr < 16; rr++) mx = fmaxf(mx, D[I][rr]);
#pragma unroll
          for (int off = 1; off < 64; off <<= 1) mx = fmaxf(mx, __shfl_xor(mx, off));
          mx = fmaxf(mx, 1e-30f);
          rsw = 1.0f / mx;
          tlog += __logf(mx);
        }
#pragma unroll
        for (int I = 0; I < 2; I++)
#pragma unroll
          for (int rr = 0; rr < 16; rr++) D[I][rr] *= rsw;
        unsigned PDt[2][4][2];
#pragma unroll
        for (int I = 0; I < 2; I++)
#pragma unroll
          for (int j = 0; j < 4; j++) {
            PDt[I][j][0] = pk2t(D[I][4 * j + 0], D[I][4 * j + 1]);
            PDt[I][j][1] = pk2t(D[I][4 * j + 2], D[I][4 * j + 3]);
          }
        if (last) {
          unsigned short* Xrow = Ptile[0] + 32 * J + nh;  // Zb row-major into Ptile[0]
#pragma unroll
          for (int I = 0; I < 2; I++)
#pragma unroll
            for (int j = 0; j < 4; j++)
#pragma unroll
              for (int pp = 0; pp < 2; pp++) {
                const int rr = 32 * I + 8 * j + 4 * hh + 2 * pp;
                Xrow[rr * 64] = (unsigned short)(PDt[I][j][pp] & 0xffffu);
                Xrow[(rr + 1) * 64] = (unsigned short)(PDt[I][j][pp] >> 16);
              }
        } else {
#pragma unroll
          for (int kap = 0; kap < 4; kap++) {
            const int Ip = kap >> 1, e2 = 2 * (kap & 1);
            unsigned x0 = PDt[Ip][e2][0], y0 = PDt[Ip][e2 + 1][0];
            unsigned x1 = PDt[Ip][e2][1], y1 = PDt[Ip][e2 + 1][1];
            pswap(x0, y0);
            pswap(x1, y1);
            Bf[kap][J][0] = x0;
            Bf[kap][J][1] = x1;
            Bf[kap][J][2] = y0;
            Bf[kap][J][3] = y1;
          }
        }
      }
    }
  }

  // T3: l=0 emission softmax, x0, single matvec vs Zb, logsumexp, output.
  const int i = L;
  const float* er0 = embed + (size_t)x[(size_t)b * L_] * 256;
  float e0 = bias[i], e1 = 0.f, e2 = 0.f, e3 = 0.f;
#pragma unroll 16
  for (int d = 0; d < 256; d += 4) {
    e0 = fmaf(er0[d + 0], W[(d + 0) * T_ + i], e0);
    e1 = fmaf(er0[d + 1], W[(d + 1) * T_ + i], e1);
    e2 = fmaf(er0[d + 2], W[(d + 2) * T_ + i], e2);
    e3 = fmaf(er0[d + 3], W[(d + 3) * T_ + i], e3);
  }
  float e = (e0 + e1) + (e2 + e3);
  float mr = e;
#pragma unroll
  for (int off = 1; off < 64; off <<= 1) mr = fmaxf(mr, __shfl_xor(mr, off));
  float pex = __expf(e - mr);
  float sr = pex;
#pragma unroll
  for (int off = 1; off < 64; off <<= 1) sr += __shfl_xor(sr, off);
  const int t0 = tg[0];
  float sc = score[b];
  sc += (__shfl(e, t0) - mr) - __logf(sr);
  sc += trans[t0] + trans[tg[L_ - 1] * T_ + 1];
  vS[i] = __expf(trans[i]) * (pex / sr);  // x0[i]; same-wave LDS, in-order
  float rl = (i < 32) ? rlog[b * C_ + i] : 0.f;
#pragma unroll
  for (int off = 1; off < 64; off <<= 1) rl += __shfl_xor(rl, off);
  const uint4* Zr = (const uint4*)Ptile[0];
  uint4 Xr[8];
#pragma unroll
  for (int t = 0; t < 8; t++) Xr[t] = Zr[i * 8 + t];
  float a0 = 0.f, a1 = 0.f, a2 = 0.f, a3 = 0.f;
#pragma unroll
  for (int t = 0; t < 8; t++) {
    float4 va = *(const float4*)&vS[8 * t];
    float4 vb = *(const float4*)&vS[8 * t + 4];
    a0 = fmaf(asf(Xr[t].x << 16), va.x, a0);
    a1 = fmaf(asf(Xr[t].x & 0xffff0000u), va.y, a1);
    a2 = fmaf(asf(Xr[t].y << 16), va.z, a2);
    a3 = fmaf(asf(Xr[t].y & 0xffff0000u), va.w, a3);
    a0 = fmaf(asf(Xr[t].z << 16), vb.x, a0);
    a1 = fmaf(asf(Xr[t].z & 0xffff0000u), vb.y, a1);
    a2 = fmaf(asf(Xr[t].w << 16), vb.z, a2);
    a3 = fmaf(asf(Xr[t].w & 0xffff0000u), vb.w, a3);
  }
  float t2 = ((a0 + a1) + (a2 + a3)) * __expf(trans[i * T_ + 1]);
#pragma unroll
  for (int off = 1; off < 64; off <<= 1) t2 += __shfl_xor(t2, off);
  if (i == 0) {
    const float logz = rl + tlog + __logf(t2);
    atomicAdd(out, -(sc - logz));
  }
}

extern "C" void kernel_launch(void* const* d_in, const int* in_sizes, int n_in,
                              void* d_out, int out_size, void* d_ws, size_t ws_size,
                              hipStream_t stream) {
  const int* x = (const int*)d_in[0];
  const int* tags = (const int*)d_in[1];
  const float* embed = (const float*)d_in[3];
  const float* W = (const float*)d_in[4];
  const float* bias = (const float*)d_in[5];
  const float* trans = (const float*)d_in[6];

  char* ws = (char*)d_ws;
  unsigned short* XT = (unsigned short*)ws;                      // 32 MB
  float* rlog = (float*)(ws + (size_t)C_ * 1048576);             // 16 KB
  float* score = (float*)((char*)rlog + 4096 * 4);               // 512 B
  unsigned* cnt = (unsigned*)((char*)score + 128 * 4);           // 512 B
  unsigned short* Wswz = (unsigned short*)((char*)cnt + 128 * 4);  // 32 KB
  float* out = (float*)d_out;

  k_prep<<<16, 256, 0, stream>>>(W, Wswz, score, cnt, out);
  k_scan<<<32 * C_, 256, 0, stream>>>(x, tags, embed, Wswz, W, bias, trans,
                                      XT, rlog, score, cnt, out);
}

// Round 19
// 195.815 us; speedup vs baseline: 1.9890x; 1.9890x over previous
//
#include <hip/hip_runtime.h>
#include <hip/hip_bf16.h>

#define B_ 128
#define L_ 1024
#define T_ 64
#define CSH 5
#define C_ 32

using short8 = __attribute__((ext_vector_type(8))) short;
using f32x4  = __attribute__((ext_vector_type(4))) float;
using f32x16 = __attribute__((ext_vector_type(16))) float;

static __device__ __forceinline__ unsigned short bfb(float x) {
  return __builtin_bit_cast(unsigned short, __float2bfloat16(x));
}
static __device__ __forceinline__ float asf(unsigned u) { return __builtin_bit_cast(float, u); }
static __device__ __forceinline__ float bf2f(unsigned short b) { return asf(((unsigned)b) << 16); }
static __device__ __forceinline__ unsigned pk2(float lo, float hi) {
  __hip_bfloat162 h = __float22bfloat162_rn(float2{lo, hi});
  unsigned u;
  __builtin_memcpy(&u, &h, 4);
  return u;
}
// packed 2xf32 -> bf16x2 dword by TRUNCATION: one v_perm_b32 (verified r8)
static __device__ __forceinline__ unsigned pk2t(float lo, float hi) {
  return __builtin_amdgcn_perm(__builtin_bit_cast(unsigned, hi),
                               __builtin_bit_cast(unsigned, lo), 0x07060302u);
}
// gfx950 half-wave exchange (verified r5)
static __device__ __forceinline__ void pswap(unsigned& x, unsigned& y) {
  asm("v_permlane32_swap_b32 %0, %1" : "+v"(x), "+v"(y));
}

// ---------- K0: build Wswz table + zero score/out ----------
__global__ __launch_bounds__(256) void k_prep(const float* __restrict__ W,
                                              unsigned short* __restrict__ Wswz,
                                              float* __restrict__ score,
                                              float* __restrict__ out) {
  if (blockIdx.x == 0) {
    if (threadIdx.x < 128) score[threadIdx.x] = 0.f;
    if (threadIdx.x == 0) out[0] = 0.f;
  }
  const int t = blockIdx.x * 256 + threadIdx.x;
  const int e = t * 4, k = e >> 6, n0 = e & 63;
  float4 w4 = *(const float4*)(W + e);
  const int base = ((k >> 5) << 11) + ((n0 >> 4) << 9) + (((k >> 3) & 3) << 7) +
                   ((n0 & 15) << 3) + (k & 7);
  Wswz[base + 0]  = bfb(w4.x);
  Wswz[base + 8]  = bfb(w4.y);
  Wswz[base + 16] = bfb(w4.z);
  Wswz[base + 24] = bfb(w4.w);
}

// ---------- K1: emission + scan + distributed gold (r13 scan + r14 gold; NO tail —
// r18 lesson: fusing the tail inflated VGPR 124->144 / LDS 16->50KB and halved
// the scan's occupancy. Cold-path code must not share the hot loop's kernel.) ----
__global__ __launch_bounds__(256) void k_scan(const int* __restrict__ x,
                                              const int* __restrict__ tags,
                                              const float* __restrict__ embed,
                                              const unsigned short* __restrict__ Wswz,
                                              const float* __restrict__ bias,
                                              const float* __restrict__ trans,
                                              unsigned short* __restrict__ XT,
                                              float* __restrict__ rlog,
                                              float* __restrict__ score) {
  __shared__ __align__(16) unsigned short Ftile[4][2048];
  const int wv = threadIdx.x >> 6, L = threadIdx.x & 63;
  const int job = blockIdx.x * 4 + wv;
  const int c = job & (C_ - 1);
  const int b = job >> CSH;
  const int K = (1023 + C_ - 1) >> CSH;
  const int a = 1 + c * K;
  const int len = min(K, 1024 - a);
  const int nh = L & 31, hh = L >> 5;
  const int m = L & 15, q = L >> 4;
  unsigned short* Ft = Ftile[wv];
  const int* tg = tags + (size_t)b * L_;

  const float bj0 = bias[m], bj1 = bias[16 + m], bj2 = bias[32 + m], bj3 = bias[48 + m];
  for (int p = 0; p < 2; p++) {
    int tok = a + 16 * p + m;
    if (tok > 1023) tok = 1023;
    const float* er = embed + (size_t)x[b * 1024 + tok] * 256;
    f32x4 acc[4] = {{0.f,0.f,0.f,0.f},{0.f,0.f,0.f,0.f},{0.f,0.f,0.f,0.f},{0.f,0.f,0.f,0.f}};
#pragma unroll
    for (int kap = 0; kap < 8; kap++) {
      float4 p0 = *(const float4*)(er + 32 * kap + 8 * q);
      float4 p1 = *(const float4*)(er + 32 * kap + 8 * q + 4);
      unsigned u0 = pk2(p0.x, p0.y), u1 = pk2(p0.z, p0.w);
      unsigned u2 = pk2(p1.x, p1.y), u3 = pk2(p1.z, p1.w);
      short8 af = __builtin_bit_cast(short8, make_uint4(u0, u1, u2, u3));
#pragma unroll
      for (int u = 0; u < 4; u++) {
        short8 bf8 = *(const short8*)&Wswz[kap * 2048 + u * 512 + q * 128 + m * 8];
        acc[u] = __builtin_amdgcn_mfma_f32_16x16x32_bf16(af, bf8, acc[u], 0, 0, 0);
      }
    }
#pragma unroll
    for (int r = 0; r < 4; r++) {
      float e0 = acc[0][r] + bj0, e1 = acc[1][r] + bj1;
      float e2 = acc[2][r] + bj2, e3 = acc[3][r] + bj3;
      float mr = fmaxf(fmaxf(e0, e1), fmaxf(e2, e3));
#pragma unroll
      for (int off = 1; off < 16; off <<= 1) mr = fmaxf(mr, __shfl_xor(mr, off));
      float x0 = __expf(e0 - mr), x1 = __expf(e1 - mr);
      float x2 = __expf(e2 - mr), x3 = __expf(e3 - mr);
      float sr = (x0 + x1) + (x2 + x3);
#pragma unroll
      for (int off = 1; off < 16; off <<= 1) sr += __shfl_xor(sr, off);
      float rs = 1.0f / sr;
      const int row = 16 * p + 4 * q + r;
      Ft[row * 64 + m]      = bfb(x0 * rs);
      Ft[row * 64 + 16 + m] = bfb(x1 * rs);
      Ft[row * 64 + 32 + m] = bfb(x2 * rs);
      Ft[row * 64 + 48 + m] = bfb(x3 * rs);
    }
  }
  // distributed gold partials (r14-verified)
  {
    float gold = 0.f;
    if (L < len) {
      const int tga = tg[a + L], tgp = tg[a - 1 + L];
      gold = __logf(bf2f(Ft[L * 64 + tga])) + trans[tgp * T_ + tga];
    }
#pragma unroll
    for (int off = 1; off < 64; off <<= 1) gold += __shfl_xor(gold, off);
    if (L == 0) atomicAdd(&score[b], gold);
  }

  short8 Af[2][4];
#pragma unroll
  for (int I = 0; I < 2; I++)
#pragma unroll
    for (int kap = 0; kap < 4; kap++) {
      short8 aa;
#pragma unroll
      for (int d = 0; d < 8; d++) {
        const int k = 16 * kap + 8 * hh + d;
        aa[d] = (short)bfb(__expf(trans[k * T_ + 32 * I + nh]));
      }
      Af[I][kap] = aa;
    }
  unsigned Bf[4][2][4];
#pragma unroll
  for (int kap = 0; kap < 4; kap++)
#pragma unroll
    for (int J = 0; J < 2; J++)
#pragma unroll
      for (int dw = 0; dw < 4; dw++) {
        int k0 = 16 * kap + 8 * hh + 2 * dw, n = 32 * J + nh;
        unsigned u = 0;
        if (k0 == n) u = 0x3F80u;
        if (k0 + 1 == n) u = 0x3F800000u;
        Bf[kap][J][dw] = u;
      }

  float logacc = 0.f;
  const f32x16 Z = {};
  for (int s = 0; s < len; s++) {  // --- r13-verified scan loop ---
    uint2 Fc[2][4];
#pragma unroll
    for (int I = 0; I < 2; I++)
#pragma unroll
      for (int j = 0; j < 4; j++)
        Fc[I][j] = *(const uint2*)&Ft[s * 64 + (16 * I + 4 * j + 2 * hh) * 2];
    const bool rn = ((s & 15) == 15);
    float rs = 1.0f;
#pragma unroll
    for (int J = 0; J < 2; J++) {
      f32x16 D[2];
#pragma unroll
      for (int I = 0; I < 2; I++) {
        short8 b0 = __builtin_bit_cast(short8,
            make_uint4(Bf[0][J][0], Bf[0][J][1], Bf[0][J][2], Bf[0][J][3]));
        f32x16 d = __builtin_amdgcn_mfma_f32_32x32x16_bf16(Af[I][0], b0, Z, 0, 0, 0);
#pragma unroll
        for (int kap = 1; kap < 4; kap++) {
          short8 bk = __builtin_bit_cast(short8,
              make_uint4(Bf[kap][J][0], Bf[kap][J][1], Bf[kap][J][2], Bf[kap][J][3]));
          d = __builtin_amdgcn_mfma_f32_32x32x16_bf16(Af[I][kap], bk, d, 0, 0, 0);
        }
        D[I] = d;
      }
#pragma unroll
      for (int I = 0; I < 2; I++)
#pragma unroll
        for (int j = 0; j < 4; j++) {
          uint2 g = Fc[I][j];
          float f0 = asf(g.x << 16), f1 = asf(g.x & 0xffff0000u);
          float f2 = asf(g.y << 16), f3 = asf(g.y & 0xffff0000u);
          D[I][4 * j + 0] *= f0;
          D[I][4 * j + 1] *= f1;
          D[I][4 * j + 2] *= f2;
          D[I][4 * j + 3] *= f3;
        }
      if (rn) {
        if (J == 0) {
          float mx = D[0][0];
#pragma unroll
          for (int I = 0; I < 2; I++)
#pragma unroll
            for (int r = 0; r < 16; r++) mx = fmaxf(mx, D[I][r]);
#pragma unroll
          for (int off = 1; off < 64; off <<= 1) mx = fmaxf(mx, __shfl_xor(mx, off));
          rs = 1.0f / mx;
          logacc += __logf(mx);
        }
#pragma unroll
        for (int I = 0; I < 2; I++)
#pragma unroll
          for (int r = 0; r < 16; r++) D[I][r] *= rs;
      }
      unsigned PDt[2][4][2];
#pragma unroll
      for (int I = 0; I < 2; I++)
#pragma unroll
        for (int j = 0; j < 4; j++) {
          PDt[I][j][0] = pk2t(D[I][4 * j + 0], D[I][4 * j + 1]);
          PDt[I][j][1] = pk2t(D[I][4 * j + 2], D[I][4 * j + 3]);
        }
      if (s == len - 1) {
        unsigned short* Xrow = XT + (size_t)job * 4096 + 32 * J + nh;
#pragma unroll
        for (int I = 0; I < 2; I++)
#pragma unroll
          for (int j = 0; j < 4; j++)
#pragma unroll
            for (int pp = 0; pp < 2; pp++) {
              const int r = 32 * I + 8 * j + 4 * hh + 2 * pp;
              Xrow[(size_t)r * 64] = (unsigned short)(PDt[I][j][pp] & 0xffffu);
              Xrow[(size_t)(r + 1) * 64] = (unsigned short)(PDt[I][j][pp] >> 16);
            }
      } else {
#pragma unroll
        for (int kap = 0; kap < 4; kap++) {
          const int Ip = kap >> 1, e2 = 2 * (kap & 1);
          unsigned x0 = PDt[Ip][e2][0], y0 = PDt[Ip][e2 + 1][0];
          unsigned x1 = PDt[Ip][e2][1], y1 = PDt[Ip][e2 + 1][1];
          pswap(x0, y0);
          pswap(x1, y1);
          Bf[kap][J][0] = x0;
          Bf[kap][J][1] = x1;
          Bf[kap][J][2] = y0;
          Bf[kap][J][3] = y1;
        }
      }
    }
  }
  if (L == 0) rlog[job] = logacc;
}

// ---------- K2: TREE TAIL as its own kernel (r18-verified T1/T2/T3), 128 blocks ----
__global__ __launch_bounds__(256) void k_tail(const unsigned short* __restrict__ XT,
                                              const float* __restrict__ rlog,
                                              const float* __restrict__ score,
                                              const int* __restrict__ x,
                                              const float* __restrict__ embed,
                                              const float* __restrict__ W,
                                              const float* __restrict__ bias,
                                              const float* __restrict__ trans,
                                              const int* __restrict__ tags,
                                              float* __restrict__ out) {
  __shared__ __align__(16) unsigned short Ptile[4][4096];  // 64x64 per wave (32 KB)
  __shared__ __align__(16) float vS[64];
  __shared__ float tlg[4];
  const int wv = threadIdx.x >> 6, L = threadIdx.x & 63;
  const int b = blockIdx.x;
  const int nh = L & 31, hh = L >> 5;
  const int* tg = tags + (size_t)b * L_;
  const f32x16 Z = {};
  unsigned Bf[4][2][4];

  // T1: wave wv computes P_wv = X_{8wv+7}···X_{8wv}, per-round renorm (log -> tlg).
  const unsigned short* Sb = XT + (size_t)b * C_ * 4096;
  {
    float plog = 0.f;
#pragma unroll
    for (int kap = 0; kap < 4; kap++)
#pragma unroll
      for (int J = 0; J < 2; J++)
#pragma unroll
        for (int dw = 0; dw < 4; dw++) {
          int k0 = 16 * kap + 8 * hh + 2 * dw, n = 32 * J + nh;
          unsigned u = 0;
          if (k0 == n) u = 0x3F80u;
          if (k0 + 1 == n) u = 0x3F800000u;
          Bf[kap][J][dw] = u;
        }
    for (int r = 0; r < 8; r++) {
      short8 Ap[2][4];
#pragma unroll
      for (int I = 0; I < 2; I++)
#pragma unroll
        for (int kap = 0; kap < 4; kap++)
          Ap[I][kap] = *(const short8*)(Sb + (size_t)(8 * wv + r) * 4096 +
                                        (32 * I + nh) * 64 + 16 * kap + 8 * hh);
      const bool last = (r == 7);
      float rsw = 1.0f;
#pragma unroll
      for (int J = 0; J < 2; J++) {
        f32x16 D[2];
#pragma unroll
        for (int I = 0; I < 2; I++) {
          short8 b0 = __builtin_bit_cast(short8,
              make_uint4(Bf[0][J][0], Bf[0][J][1], Bf[0][J][2], Bf[0][J][3]));
          f32x16 d = __builtin_amdgcn_mfma_f32_32x32x16_bf16(Ap[I][0], b0, Z, 0, 0, 0);
#pragma unroll
          for (int kap = 1; kap < 4; kap++) {
            short8 bk = __builtin_bit_cast(short8,
                make_uint4(Bf[kap][J][0], Bf[kap][J][1], Bf[kap][J][2], Bf[kap][J][3]));
            d = __builtin_amdgcn_mfma_f32_32x32x16_bf16(Ap[I][kap], bk, d, 0, 0, 0);
          }
          D[I] = d;
        }
        if (J == 0) {
          float mx = D[0][0];
#pragma unroll
          for (int I = 0; I < 2; I++)
#pragma unroll
            for (int rr = 0; rr < 16; rr++) mx = fmaxf(mx, D[I][rr]);
#pragma unroll
          for (int off = 1; off < 64; off <<= 1) mx = fmaxf(mx, __shfl_xor(mx, off));
          mx = fmaxf(mx, 1e-30f);
          rsw = 1.0f / mx;
          plog += __logf(mx);
        }
#pragma unroll
        for (int I = 0; I < 2; I++)
#pragma unroll
          for (int rr = 0; rr < 16; rr++) D[I][rr] *= rsw;
        unsigned PDt[2][4][2];
#pragma unroll
        for (int I = 0; I < 2; I++)
#pragma unroll
          for (int j = 0; j < 4; j++) {
            PDt[I][j][0] = pk2t(D[I][4 * j + 0], D[I][4 * j + 1]);
            PDt[I][j][1] = pk2t(D[I][4 * j + 2], D[I][4 * j + 3]);
          }
        if (last) {
          unsigned short* Xrow = Ptile[wv] + 32 * J + nh;
#pragma unroll
          for (int I = 0; I < 2; I++)
#pragma unroll
            for (int j = 0; j < 4; j++)
#pragma unroll
              for (int pp = 0; pp < 2; pp++) {
                const int rr = 32 * I + 8 * j + 4 * hh + 2 * pp;
                Xrow[rr * 64] = (unsigned short)(PDt[I][j][pp] & 0xffffu);
                Xrow[(rr + 1) * 64] = (unsigned short)(PDt[I][j][pp] >> 16);
              }
        } else {
#pragma unroll
          for (int kap = 0; kap < 4; kap++) {
            const int Ip = kap >> 1, e2 = 2 * (kap & 1);
            unsigned x0 = PDt[Ip][e2][0], y0 = PDt[Ip][e2 + 1][0];
            unsigned x1 = PDt[Ip][e2][1], y1 = PDt[Ip][e2 + 1][1];
            pswap(x0, y0);
            pswap(x1, y1);
            Bf[kap][J][0] = x0;
            Bf[kap][J][1] = x1;
            Bf[kap][J][2] = y0;
            Bf[kap][J][3] = y1;
          }
        }
      }
    }
    if (L == 0) tlg[wv] = plog;
  }
  __syncthreads();
  if (threadIdx.x >= 64) return;  // wave 0 finishes alone

  // T2: Zb = P_3 · P_2 · P_1 · P_0 from Ptile; per-round renorm + log.
  float tlog = (tlg[0] + tlg[1]) + (tlg[2] + tlg[3]);
  {
#pragma unroll
    for (int kap = 0; kap < 4; kap++)
#pragma unroll
      for (int J = 0; J < 2; J++)
#pragma unroll
        for (int dw = 0; dw < 4; dw++) {
          int k0 = 16 * kap + 8 * hh + 2 * dw, n = 32 * J + nh;
          unsigned u = 0;
          if (k0 == n) u = 0x3F80u;
          if (k0 + 1 == n) u = 0x3F800000u;
          Bf[kap][J][dw] = u;
        }
    for (int r = 0; r < 4; r++) {
      short8 Ap[2][4];
#pragma unroll
      for (int I = 0; I < 2; I++)
#pragma unroll
        for (int kap = 0; kap < 4; kap++)
          Ap[I][kap] = *(const short8*)&Ptile[r][(32 * I + nh) * 64 + 16 * kap + 8 * hh];
      const bool last = (r == 3);
      float rsw = 1.0f;
#pragma unroll
      for (int J = 0; J < 2; J++) {
        f32x16 D[2];
#pragma unroll
        for (int I = 0; I < 2; I++) {
          short8 b0 = __builtin_bit_cast(short8,
              make_uint4(Bf[0][J][0], Bf[0][J][1], Bf[0][J][2], Bf[0][J][3]));
          f32x16 d = __builtin_amdgcn_mfma_f32_32x32x16_bf16(Ap[I][0], b0, Z, 0, 0, 0);
#pragma unroll
          for (int kap = 1; kap < 4; kap++) {
            short8 bk = __builtin_bit_cast(short8,
                make_uint4(Bf[kap][J][0], Bf[kap][J][1], Bf[kap][J][2], Bf[kap][J][3]));
            d = __builtin_amdgcn_mfma_f32_32x32x16_bf16(Ap[I][kap], bk, d, 0, 0, 0);
          }
          D[I] = d;
        }
        if (J == 0) {
          float mx = D[0][0];
#pragma unroll
          for (int I = 0; I < 2; I++)
#pragma unroll
            for (int rr = 0; rr < 16; rr++) mx = fmaxf(mx, D[I][rr]);
#pragma unroll
          for (int off = 1; off < 64; off <<= 1) mx = fmaxf(mx, __shfl_xor(mx, off));
          mx = fmaxf(mx, 1e-30f);
          rsw = 1.0f / mx;
          tlog += __logf(mx);
        }
#pragma unroll
        for (int I = 0; I < 2; I++)
#pragma unroll
          for (int rr = 0; rr < 16; rr++) D[I][rr] *= rsw;
        unsigned PDt[2][4][2];
#pragma unroll
        for (int I = 0; I < 2; I++)
#pragma unroll
          for (int j = 0; j < 4; j++) {
            PDt[I][j][0] = pk2t(D[I][4 * j + 0], D[I][4 * j + 1]);
            PDt[I][j][1] = pk2t(D[I][4 * j + 2], D[I][4 * j + 3]);
          }
        if (last) {
          unsigned short* Xrow = Ptile[0] + 32 * J + nh;
#pragma unroll
          for (int I = 0; I < 2; I++)
#pragma unroll
            for (int j = 0; j < 4; j++)
#pragma unroll
              for (int pp = 0; pp < 2; pp++) {
                const int rr = 32 * I + 8 * j + 4 * hh + 2 * pp;
                Xrow[rr * 64] = (unsigned short)(PDt[I][j][pp] & 0xffffu);
                Xrow[(rr + 1) * 64] = (unsigned short)(PDt[I][j][pp] >> 16);
              }
        } else {
#pragma unroll
          for (int kap = 0; kap < 4; kap++) {
            const int Ip = kap >> 1, e2 = 2 * (kap & 1);
            unsigned x0 = PDt[Ip][e2][0], y0 = PDt[Ip][e2 + 1][0];
            unsigned x1 = PDt[Ip][e2][1], y1 = PDt[Ip][e2 + 1][1];
            pswap(x0, y0);
            pswap(x1, y1);
            Bf[kap][J][0] = x0;
            Bf[kap][J][1] = x1;
            Bf[kap][J][2] = y0;
            Bf[kap][J][3] = y1;
          }
        }
      }
    }
  }

  // T3: l=0 emission softmax, x0, single matvec vs Zb, logsumexp, output.
  const int i = L;
  const float* er0 = embed + (size_t)x[(size_t)b * L_] * 256;
  float e0 = bias[i], e1 = 0.f, e2 = 0.f, e3 = 0.f;
#pragma unroll 16
  for (int d = 0; d < 256; d += 4) {
    e0 = fmaf(er0[d + 0], W[(d + 0) * T_ + i], e0);
    e1 = fmaf(er0[d + 1], W[(d + 1) * T_ + i], e1);
    e2 = fmaf(er0[d + 2], W[(d + 2) * T_ + i], e2);
    e3 = fmaf(er0[d + 3], W[(d + 3) * T_ + i], e3);
  }
  float e = (e0 + e1) + (e2 + e3);
  float mr = e;
#pragma unroll
  for (int off = 1; off < 64; off <<= 1) mr = fmaxf(mr, __shfl_xor(mr, off));
  float pex = __expf(e - mr);
  float sr = pex;
#pragma unroll
  for (int off = 1; off < 64; off <<= 1) sr += __shfl_xor(sr, off);
  const int t0 = tg[0];
  float sc = score[b];
  sc += (__shfl(e, t0) - mr) - __logf(sr);
  sc += trans[t0] + trans[tg[L_ - 1] * T_ + 1];
  vS[i] = __expf(trans[i]) * (pex / sr);  // x0[i]; same-wave LDS, in-order
  float rl = (i < 32) ? rlog[b * C_ + i] : 0.f;
#pragma unroll
  for (int off = 1; off < 64; off <<= 1) rl += __shfl_xor(rl, off);
  const uint4* Zr = (const uint4*)Ptile[0];
  uint4 Xr[8];
#pragma unroll
  for (int t = 0; t < 8; t++) Xr[t] = Zr[i * 8 + t];
  float a0 = 0.f, a1 = 0.f, a2 = 0.f, a3 = 0.f;
#pragma unroll
  for (int t = 0; t < 8; t++) {
    float4 va = *(const float4*)&vS[8 * t];
    float4 vb = *(const float4*)&vS[8 * t + 4];
    a0 = fmaf(asf(Xr[t].x << 16), va.x, a0);
    a1 = fmaf(asf(Xr[t].x & 0xffff0000u), va.y, a1);
    a2 = fmaf(asf(Xr[t].y << 16), va.z, a2);
    a3 = fmaf(asf(Xr[t].y & 0xffff0000u), va.w, a3);
    a0 = fmaf(asf(Xr[t].z << 16), vb.x, a0);
    a1 = fmaf(asf(Xr[t].z & 0xffff0000u), vb.y, a1);
    a2 = fmaf(asf(Xr[t].w << 16), vb.z, a2);
    a3 = fmaf(asf(Xr[t].w & 0xffff0000u), vb.w, a3);
  }
  float t2 = ((a0 + a1) + (a2 + a3)) * __expf(trans[i * T_ + 1]);
#pragma unroll
  for (int off = 1; off < 64; off <<= 1) t2 += __shfl_xor(t2, off);
  if (i == 0) {
    const float logz = rl + tlog + __logf(t2);
    atomicAdd(out, -(sc - logz));
  }
}

extern "C" void kernel_launch(void* const* d_in, const int* in_sizes, int n_in,
                              void* d_out, int out_size, void* d_ws, size_t ws_size,
                              hipStream_t stream) {
  const int* x = (const int*)d_in[0];
  const int* tags = (const int*)d_in[1];
  const float* embed = (const float*)d_in[3];
  const float* W = (const float*)d_in[4];
  const float* bias = (const float*)d_in[5];
  const float* trans = (const float*)d_in[6];

  char* ws = (char*)d_ws;
  unsigned short* XT = (unsigned short*)ws;                      // 32 MB
  float* rlog = (float*)(ws + (size_t)C_ * 1048576);             // 16 KB
  float* score = (float*)((char*)rlog + 4096 * 4);               // 512 B
  unsigned short* Wswz = (unsigned short*)((char*)score + 128 * 4);  // 32 KB
  float* out = (float*)d_out;

  k_prep<<<16, 256, 0, stream>>>(W, Wswz, score, out);
  k_scan<<<32 * C_, 256, 0, stream>>>(x, tags, embed, Wswz, bias, trans, XT, rlog, score);
  k_tail<<<B_, 256, 0, stream>>>(XT, rlog, score, x, embed, W, bias, trans, tags, out);
}